// Round 11
// baseline (395.852 us; speedup 1.0000x reference)
//
#include <hip/hip_runtime.h>
#include <hip/hip_bf16.h>
#include <math.h>

#define DM 1024
#define DS 16
#define DI 2048
#define NB 2
#define LL 2048
#define BL (NB*LL)
#define LC 32
#define NC (LL/LC)   // 64

typedef __attribute__((ext_vector_type(8))) short short8;
typedef __attribute__((ext_vector_type(8))) unsigned short ushort8;
typedef __attribute__((ext_vector_type(4))) float f32x4;

__device__ __forceinline__ float silu_f(float x){ return x / (1.f + __expf(-x)); }
__device__ __forceinline__ float softplus_f(float x){ return (x > 15.f) ? x : log1pf(__expf(x)); }
__device__ __forceinline__ unsigned short f2bf(float f){
  unsigned u = __float_as_uint(f);
  u += 0x7fff + ((u >> 16) & 1);
  return (unsigned short)(u >> 16);
}
__device__ __forceinline__ float bf2f(unsigned short v){
  return __uint_as_float(((unsigned)v) << 16);
}

// ---------------- fp32 -> bf16 convert (single segment) ----------------
__global__ __launch_bounds__(256) void f2b_k(const float* __restrict__ src,
                                             unsigned short* __restrict__ dst, int n)
{
  int i = (blockIdx.x * 256 + threadIdx.x) * 8;
  if (i >= n) return;
  float4 v0 = *(const float4*)&src[i];
  float4 v1 = *(const float4*)&src[i + 4];
  ushort8 o;
  o[0]=f2bf(v0.x); o[1]=f2bf(v0.y); o[2]=f2bf(v0.z); o[3]=f2bf(v0.w);
  o[4]=f2bf(v1.x); o[5]=f2bf(v1.y); o[6]=f2bf(v1.z); o[7]=f2bf(v1.w);
  *(ushort8*)&dst[i] = o;
}

// ---------------- fp32 -> bf16 convert, 4 segments in one launch -------
__global__ __launch_bounds__(256) void f2b_multi(
    const float* __restrict__ s0, unsigned short* __restrict__ d0, int c0,
    const float* __restrict__ s1, unsigned short* __restrict__ d1, int c1,
    const float* __restrict__ s2, unsigned short* __restrict__ d2, int c2,
    const float* __restrict__ s3, unsigned short* __restrict__ d3, int c3)
{
  int b = blockIdx.x;
  const float* s; unsigned short* d;
  if (b < c0)              { s = s0; d = d0; }
  else if ((b -= c0) < c1) { s = s1; d = d1; }
  else if ((b -= c1) < c2) { s = s2; d = d2; }
  else                     { b -= c2; s = s3; d = d3; }
  int i = (b * 256 + threadIdx.x) * 8;
  float4 v0 = *(const float4*)&s[i];
  float4 v1 = *(const float4*)&s[i + 4];
  ushort8 o;
  o[0]=f2bf(v0.x); o[1]=f2bf(v0.y); o[2]=f2bf(v0.z); o[3]=f2bf(v0.w);
  o[4]=f2bf(v1.x); o[5]=f2bf(v1.y); o[6]=f2bf(v1.z); o[7]=f2bf(v1.w);
  *(ushort8*)&d[i] = o;
}

// ---------------- bf16 MFMA GEMM, LDS-lean wave tiles ------------------
// C[M][N] = A[M][K] @ Bw[N][K]^T.  BM=256, BN=128, BK=64, 256 threads
// (4 waves 2Mx2N, wave tile 128x64).  KEY: 128x64 wave tile needs
// (128+64)*64*2 = 24 KB LDS-read per 64 MFMA = 375 B/MFMA (vs 512 for
// 64x64) -- under the ~310-400 B/MFMA LDS BW budget, so the ds_read
// pipe stops being the wall.  Single 48 KB LDS buffer, plain
// 2-barrier loop; per-ks read->MFMA keeps operand VGPRs bounded.
// XOR swizzle ch^=(row&7) on BOTH stage source and ds_read.
// Bijective XCD swizzle (grid % 8 == 0).
template<int EPI, int OUTBF>
__global__ __launch_bounds__(256, 2) void gemm8(
    const unsigned short* __restrict__ A, const unsigned short* __restrict__ Bw,
    const float* __restrict__ bias, void* __restrict__ Cp,
    int N, int K)
{
  __shared__ unsigned short lds[384 * 64];   // A rows 0-255, B rows 256-383
  const int t = threadIdx.x;
  const int wid = t >> 6, lane = t & 63;
  const int nbx = N >> 7;
  const int cpx = (int)gridDim.x >> 3;
  const int bid = (int)blockIdx.x;
  const int swz = (bid & 7) * cpx + (bid >> 3);
  const int bm = (swz / nbx) << 8, bn = (swz % nbx) << 7;
  const int wm = (wid >> 1) * 128, wn = (wid & 1) * 64;
  const int ln15 = lane & 15, l16 = lane >> 4, lx7 = lane & 7;
  const int srow = lane >> 3;                // 0..7
  const int sch  = lx7 ^ srow;               // inverse-swizzled source chunk

  f32x4 acc[8][4] = {};

  for (int kt = 0; kt < (K >> 6); kt++) {
    const int k0 = kt << 6;
    __syncthreads();                         // prev-iter LDS reads done
    #pragma unroll
    for (int s = 0; s < 12; s++) {
      int g = wid * 12 + s;                  // 0..47, wave-uniform
      int row = g * 8 + srow;                // 0..383
      const unsigned short* src;
      if (g < 32) src = A  + (size_t)(bm + row) * K + k0 + sch * 8;
      else        src = Bw + (size_t)(bn + row - 256) * K + k0 + sch * 8;
      __builtin_amdgcn_global_load_lds(
          (const __attribute__((address_space(1))) void*)src,
          (__attribute__((address_space(3))) void*)(&lds[g * 512]), 16, 0, 0);
    }
    __syncthreads();                         // stage landed (implicit drain)
    #pragma unroll
    for (int ks = 0; ks < 2; ks++) {
      const int cc = ((ks << 2) + l16) ^ lx7;
      short8 af[8], bfr[4];
      #pragma unroll
      for (int i = 0; i < 8; i++)
        af[i] = *(const short8*)&lds[(wm + i * 16 + ln15) * 64 + cc * 8];
      #pragma unroll
      for (int j = 0; j < 4; j++)
        bfr[j] = *(const short8*)&lds[(256 + wn + j * 16 + ln15) * 64 + cc * 8];
      #pragma unroll
      for (int i = 0; i < 8; i++)
        #pragma unroll
        for (int j = 0; j < 4; j++)
          acc[i][j] = __builtin_amdgcn_mfma_f32_16x16x32_bf16(af[i], bfr[j], acc[i][j], 0, 0, 0);
    }
  }

  #pragma unroll
  for (int i = 0; i < 8; i++) {
    #pragma unroll
    for (int j = 0; j < 4; j++) {
      int col = bn + wn + j * 16 + ln15;
      float bv = (EPI == 1) ? bias[col] : 0.f;
      #pragma unroll
      for (int r = 0; r < 4; r++) {
        int row = bm + wm + i * 16 + l16 * 4 + r;
        float v = acc[i][j][r];
        if (EPI == 1) v = softplus_f(v + bv);
        if (OUTBF) ((unsigned short*)Cp)[(size_t)row * N + col] = f2bf(v);
        else       ((float*)Cp)[(size_t)row * N + col] = v;
      }
    }
  }
}

// ---------------- causal depthwise conv (k=4) + bias + SiLU -> bf16 ----
__global__ __launch_bounds__(256) void conv_silu_k(
    const unsigned short* __restrict__ xz, const float* __restrict__ cw,
    const float* __restrict__ cb, unsigned short* __restrict__ xa)
{
  int v = blockIdx.x * 256 + threadIdx.x;   // over BL*DI/8
  int d8 = (v & (DI/8 - 1)) * 8;
  int bl = v >> 8;
  int l  = bl & (LL - 1);
  float acc[8];
  #pragma unroll
  for (int j = 0; j < 8; j++) acc[j] = cb[d8 + j];
  size_t rowb = (size_t)bl * (2 * DI) + d8;
  #pragma unroll
  for (int k = 0; k < 4; k++) {
    int ls = l - 3 + k;
    if (ls >= 0) {
      ushort8 xv = *(const ushort8*)&xz[rowb + (size_t)(k - 3) * (2 * DI)];
      #pragma unroll
      for (int j = 0; j < 8; j++) acc[j] += bf2f(xv[j]) * cw[(d8 + j) * 4 + k];
    }
  }
  ushort8 o;
  #pragma unroll
  for (int j = 0; j < 8; j++) o[j] = f2bf(silu_f(acc[j]));
  *(ushort8*)&xa[(size_t)bl * DI + d8] = o;
}

// ---------------- bc = xa @ x_proj_w^T  (N=32) -------------------------
__global__ __launch_bounds__(256) void bc_k(
    const unsigned short* __restrict__ xa, const unsigned short* __restrict__ w,
    float* __restrict__ bc)
{
  __shared__ unsigned short sx[8 * DI];
  const int t = threadIdx.x;
  const size_t base = (size_t)blockIdx.x * 8 * DI;
  #pragma unroll
  for (int it = 0; it < 8; it++) {
    int v = t + it * 256;
    *(ushort8*)&sx[v * 8] = *(const ushort8*)&xa[base + (size_t)v * 8];
  }
  __syncthreads();
  const int m = t >> 5, n = t & 31;
  const unsigned short* wr = w + (size_t)n * DI;
  const unsigned short* xr = sx + m * DI;
  float acc = 0.f;
  #pragma unroll 4
  for (int k = 0; k < DI; k += 8) {
    ushort8 xv = *(const ushort8*)&xr[k];
    ushort8 wv = *(const ushort8*)&wr[k];
    #pragma unroll
    for (int j = 0; j < 8; j++) acc += bf2f(xv[j]) * bf2f(wv[j]);
  }
  bc[(size_t)(blockIdx.x * 8 + m) * 32 + n] = acc;
}

// ---------------- chunked selective scan (dlt in bf16) -----------------
__global__ __launch_bounds__(256) void scan_part1(
    const unsigned short* __restrict__ dlt, const unsigned short* __restrict__ xa,
    const float* __restrict__ bc, const float* __restrict__ A_log,
    float* __restrict__ S_arr, float* __restrict__ sumdlt)
{
  const int bid = blockIdx.x;           // NB*NC*8 = 1024
  const int b = bid >> 9;
  const int c = (bid >> 3) & (NC - 1);
  const int dg = bid & 7;
  const int t = threadIdx.x;
  const int d = dg * 256 + t;
  float Ac[16];
  #pragma unroll
  for (int n = 0; n < 16; n++) Ac[n] = -__expf(A_log[d * 16 + n]);
  __shared__ float sB[LC][16];
  for (int e = t; e < LC * 16; e += 256) {
    int l = e >> 4, n = e & 15;
    sB[l][n] = bc[(size_t)(b * LL + c * LC + l) * 32 + n];
  }
  __syncthreads();
  float h[16] = {};
  float sd = 0.f;
  size_t rowbase = (size_t)(b * LL + c * LC) * DI + d;
  for (int l = 0; l < LC; l++) {
    float dl = bf2f(dlt[rowbase + (size_t)l * DI]);
    float u  = bf2f(xa[rowbase + (size_t)l * DI]);
    float w = dl * u;
    sd += dl;
    #pragma unroll
    for (int n = 0; n < 16; n++) {
      float dA = __expf(dl * Ac[n]);
      h[n] = dA * h[n] + w * sB[l][n];
    }
  }
  float* Sp = S_arr + ((size_t)(b * NC + c) * DI + d) * 16;
  #pragma unroll
  for (int n = 0; n < 16; n++) Sp[n] = h[n];
  sumdlt[(size_t)(b * NC + c) * DI + d] = sd;
}

__global__ __launch_bounds__(256) void scan_combine(
    const float* __restrict__ A_log, const float* __restrict__ sumdlt,
    float* __restrict__ S_arr)
{
  int tid = blockIdx.x * 256 + threadIdx.x;   // NB*DI*16 = 65536
  int n = tid & 15;
  int d = (tid >> 4) & (DI - 1);
  int b = tid >> 15;
  float Ac = -__expf(A_log[d * 16 + n]);
  float h = 0.f;
  for (int c = 0; c < NC; c++) {
    size_t idx = ((size_t)(b * NC + c) * DI + d) * 16 + n;
    float S = S_arr[idx];
    float P = __expf(sumdlt[(size_t)(b * NC + c) * DI + d] * Ac);
    S_arr[idx] = h;
    h = P * h + S;
  }
}

__global__ __launch_bounds__(256) void scan_part2(
    const unsigned short* __restrict__ dlt, const unsigned short* __restrict__ xa,
    const float* __restrict__ bc, const float* __restrict__ A_log,
    const float* __restrict__ Dp, const unsigned short* __restrict__ xz,
    const float* __restrict__ Hin, unsigned short* __restrict__ y)
{
  const int bid = blockIdx.x;
  const int b = bid >> 9;
  const int c = (bid >> 3) & (NC - 1);
  const int dg = bid & 7;
  const int t = threadIdx.x;
  const int d = dg * 256 + t;
  float Ac[16];
  #pragma unroll
  for (int n = 0; n < 16; n++) Ac[n] = -__expf(A_log[d * 16 + n]);
  __shared__ float sB[LC][16];
  __shared__ float sC[LC][16];
  for (int e = t; e < LC * 16; e += 256) {
    int l = e >> 4, n = e & 15;
    size_t row = (size_t)(b * LL + c * LC + l) * 32;
    sB[l][n] = bc[row + n];
    sC[l][n] = bc[row + 16 + n];
  }
  __syncthreads();
  float h[16];
  const float* Hp = Hin + ((size_t)(b * NC + c) * DI + d) * 16;
  #pragma unroll
  for (int n = 0; n < 16; n++) h[n] = Hp[n];
  const float Dv = Dp[d];
  size_t rowbase = (size_t)(b * LL + c * LC) * DI + d;
  for (int l = 0; l < LC; l++) {
    float dl = bf2f(dlt[rowbase + (size_t)l * DI]);
    float u  = bf2f(xa[rowbase + (size_t)l * DI]);
    float w = dl * u;
    float ya = 0.f;
    #pragma unroll
    for (int n = 0; n < 16; n++) {
      float dA = __expf(dl * Ac[n]);
      h[n] = dA * h[n] + w * sB[l][n];
      ya += h[n] * sC[l][n];
    }
    float zz = bf2f(xz[(size_t)(b * LL + c * LC + l) * (2 * DI) + DI + d]);
    y[rowbase + (size_t)l * DI] = f2bf((ya + u * Dv) * silu_f(zz));
  }
}

extern "C" void kernel_launch(void* const* d_in, const int* in_sizes, int n_in,
                              void* d_out, int out_size, void* d_ws, size_t ws_size,
                              hipStream_t stream)
{
  const float* x    = (const float*)d_in[0];
  const float* Win  = (const float*)d_in[1];
  const float* cw   = (const float*)d_in[2];
  const float* cb   = (const float*)d_in[3];
  const float* Wxp  = (const float*)d_in[4];
  const float* Wdt  = (const float*)d_in[5];
  const float* bdt  = (const float*)d_in[6];
  const float* Alog = (const float*)d_in[7];
  const float* Dp   = (const float*)d_in[8];
  const float* Wout = (const float*)d_in[9];
  float* out = (float*)d_out;

  float* ws = (float*)d_ws;
  unsigned short* dlt_bf = (unsigned short*)ws;  // 8,388,608 us (uses half of old slot)
  float* bcb    = ws + 8388608;              //    131,072 f
  float* S_arr  = bcb + 131072;              //  4,194,304 f
  float* sumdlt = S_arr + 4194304;           //    262,144 f
  unsigned short* xz_bf = (unsigned short*)(sumdlt + 262144); // 16,777,216 us
  unsigned short* xa_bf = xz_bf + 16777216;  //  8,388,608 us
  unsigned short* y_bf  = xa_bf + 8388608;   //  8,388,608 us
  unsigned short* x_bf  = y_bf;              // 4,194,304 us (dead before y written)
  unsigned short* win_bf= y_bf + 4194304;    // 4,194,304 us (dead before y written)
  unsigned short* wbuf  = y_bf + 8388608;    //  4,194,304 us (Wdt, then Wout)
  unsigned short* wxp_bf= wbuf + 4194304;    //     65,536 us

  // 0) upfront conversions: x, Win, Wdt, Wxp (counts in 2048-elem blocks)
  f2b_multi<<<dim3(2048 + 2048 + 2048 + 32), dim3(256), 0, stream>>>(
      x, x_bf, 2048, Win, win_bf, 2048, Wdt, wbuf, 2048, Wxp, wxp_bf, 32);
  // 1) xz = x @ in_proj_w^T   [4096 x 4096], K=1024 -> bf16   grid 16x32=512
  gemm8<0,1><<<dim3(512), dim3(256), 0, stream>>>(x_bf, win_bf, nullptr, xz_bf, 2*DI, DM);
  // 2) x_act = silu(causal_conv(x_ssm)) -> bf16
  conv_silu_k<<<dim3(BL*DI/8/256), dim3(256), 0, stream>>>(xz_bf, cw, cb, xa_bf);
  // 3) delta = softplus(x_act @ dt_proj_w^T + b)  [4096x2048] K=2048 -> bf16, grid 256
  gemm8<1,1><<<dim3(256), dim3(256), 0, stream>>>(xa_bf, wbuf, bdt, dlt_bf, DI, DI);
  // convert Wout into wbuf (stream-ordered after dt GEMM consumed Wdt)
  f2b_k<<<dim3(DM*DI/2048), dim3(256), 0, stream>>>(Wout, wbuf, DM*DI);
  // 4) bc = x_act @ x_proj_w^T   [4096 x 32]
  bc_k<<<dim3(BL/8), dim3(256), 0, stream>>>(xa_bf, wxp_bf, bcb);
  // 5) chunked selective scan
  scan_part1<<<dim3(NB*NC*8), dim3(256), 0, stream>>>(dlt_bf, xa_bf, bcb, Alog, S_arr, sumdlt);
  scan_combine<<<dim3(NB*DI*DS/256), dim3(256), 0, stream>>>(Alog, sumdlt, S_arr);
  scan_part2<<<dim3(NB*NC*8), dim3(256), 0, stream>>>(dlt_bf, xa_bf, bcb, Alog, Dp, xz_bf, S_arr, y_bf);
  // 6) out = y @ out_proj_w^T   [4096 x 1024], K=2048 -> fp32  grid 16x8=128
  gemm8<0,0><<<dim3(128), dim3(256), 0, stream>>>(y_bf, wbuf, nullptr, out, DM, DI);
}

// Round 12
// 335.376 us; speedup vs baseline: 1.1803x; 1.1803x over previous
//
#include <hip/hip_runtime.h>
#include <hip/hip_bf16.h>
#include <math.h>

#define DM 1024
#define DS 16
#define DI 2048
#define NB 2
#define LL 2048
#define BL (NB*LL)
#define LC 32
#define NC (LL/LC)   // 64

typedef __attribute__((ext_vector_type(8))) short short8;
typedef __attribute__((ext_vector_type(8))) unsigned short ushort8;
typedef __attribute__((ext_vector_type(4))) float f32x4;

__device__ __forceinline__ float silu_f(float x){ return x / (1.f + __expf(-x)); }
__device__ __forceinline__ float softplus_f(float x){ return (x > 15.f) ? x : log1pf(__expf(x)); }
__device__ __forceinline__ unsigned short f2bf(float f){
  unsigned u = __float_as_uint(f);
  u += 0x7fff + ((u >> 16) & 1);
  return (unsigned short)(u >> 16);
}
__device__ __forceinline__ float bf2f(unsigned short v){
  return __uint_as_float(((unsigned)v) << 16);
}

// ---------------- fp32 -> bf16 convert (single segment) ----------------
__global__ __launch_bounds__(256) void f2b_k(const float* __restrict__ src,
                                             unsigned short* __restrict__ dst, int n)
{
  int i = (blockIdx.x * 256 + threadIdx.x) * 8;
  if (i >= n) return;
  float4 v0 = *(const float4*)&src[i];
  float4 v1 = *(const float4*)&src[i + 4];
  ushort8 o;
  o[0]=f2bf(v0.x); o[1]=f2bf(v0.y); o[2]=f2bf(v0.z); o[3]=f2bf(v0.w);
  o[4]=f2bf(v1.x); o[5]=f2bf(v1.y); o[6]=f2bf(v1.z); o[7]=f2bf(v1.w);
  *(ushort8*)&dst[i] = o;
}

// ---------------- fp32 -> bf16 convert, 4 segments in one launch -------
__global__ __launch_bounds__(256) void f2b_multi(
    const float* __restrict__ s0, unsigned short* __restrict__ d0, int c0,
    const float* __restrict__ s1, unsigned short* __restrict__ d1, int c1,
    const float* __restrict__ s2, unsigned short* __restrict__ d2, int c2,
    const float* __restrict__ s3, unsigned short* __restrict__ d3, int c3)
{
  int b = blockIdx.x;
  const float* s; unsigned short* d;
  if (b < c0)              { s = s0; d = d0; }
  else if ((b -= c0) < c1) { s = s1; d = d1; }
  else if ((b -= c1) < c2) { s = s2; d = d2; }
  else                     { b -= c2; s = s3; d = d3; }
  int i = (b * 256 + threadIdx.x) * 8;
  float4 v0 = *(const float4*)&s[i];
  float4 v1 = *(const float4*)&s[i + 4];
  ushort8 o;
  o[0]=f2bf(v0.x); o[1]=f2bf(v0.y); o[2]=f2bf(v0.z); o[3]=f2bf(v0.w);
  o[4]=f2bf(v1.x); o[5]=f2bf(v1.y); o[6]=f2bf(v1.z); o[7]=f2bf(v1.w);
  *(ushort8*)&d[i] = o;
}

// ---------------- 256-row-tile bf16 MFMA GEMM (round-4 verified) -------
// C[M][N] = A[M][K] @ Bw[N][K]^T.  BM=256, BK=64, BN in {256,128,64}.
// 8 waves as 2(M) x 4(N): per-wave 128 x BN/4.  Double-buffered LDS,
// stage(t+1) issued before compute(t), one __syncthreads per K-tile.
// XOR swizzle ch^=(row&7) on BOTH stage source and ds_read (0 conflicts).
// XCD swizzle (grid always 256).  Best measured: 70 us @ 34 GF.
template<int BN, int EPI, int OUTBF>
__global__ __launch_bounds__(512, 2) void gemm2(
    const unsigned short* __restrict__ A, const unsigned short* __restrict__ Bw,
    const float* __restrict__ bias, void* __restrict__ Cp,
    int M, int N, int K)
{
  constexpr int BM = 256;
  constexpr int NR = BN / 64;                 // N-frags per wave: 4/2/1
  __shared__ unsigned short lds[2][(BM + BN) * 64];
  const int t = threadIdx.x;
  const int wid = t >> 6, lane = t & 63;
  const int nbx = N / BN;
  const int cpx = (nbx * (M / BM)) >> 3;      // grid always 256 -> cpx=32
  const int bid = (int)blockIdx.x;
  const int swz = (bid & 7) * cpx + (bid >> 3);   // XCD-contiguous logical tiles
  const int bm = (swz / nbx) * BM, bn = (swz % nbx) * BN;
  const int wm = (wid >> 2) * 128, wn = (wid & 3) * (BN / 4);
  const int srow8 = lane >> 3;                // 0..7
  const int sch   = lane & 7;                 // 16B chunk 0..7

  f32x4 acc[8][NR] = {};

  auto stage = [&](int buf, int k0) {
    #pragma unroll
    for (int p = 0; p < BM / 64; p++) {
      int row = p * 64 + wid * 8 + srow8;
      int ch = sch ^ (row & 7);
      __builtin_amdgcn_global_load_lds(
        (const __attribute__((address_space(1))) void*)(A + (size_t)(bm + row) * K + k0 + ch * 8),
        (__attribute__((address_space(3))) void*)(&lds[buf][(p * 64 + wid * 8) * 64]), 16, 0, 0);
    }
    #pragma unroll
    for (int p = 0; p < BN / 64; p++) {
      int row = p * 64 + wid * 8 + srow8;
      int ch = sch ^ (row & 7);
      __builtin_amdgcn_global_load_lds(
        (const __attribute__((address_space(1))) void*)(Bw + (size_t)(bn + row) * K + k0 + ch * 8),
        (__attribute__((address_space(3))) void*)(&lds[buf][(BM + p * 64 + wid * 8) * 64]), 16, 0, 0);
    }
  };

  stage(0, 0);
  __syncthreads();
  const int nk = K / 64;
  int cur = 0;
  for (int kt = 0; kt < nk; kt++) {
    if (kt + 1 < nk) stage(cur ^ 1, (kt + 1) * 64);   // overlap with MFMA below
    const unsigned short* bufA = &lds[cur][0];
    const unsigned short* bufB = &lds[cur][BM * 64];
    #pragma unroll
    for (int ks = 0; ks < 2; ks++) {
      short8 af[8], bfr[NR];
      #pragma unroll
      for (int i = 0; i < 8; i++) {
        int r = wm + i * 16 + (lane & 15);
        int c = ((ks << 2) + (lane >> 4)) ^ (r & 7);
        af[i] = *(const short8*)&bufA[r * 64 + c * 8];
      }
      #pragma unroll
      for (int j = 0; j < NR; j++) {
        int r = wn + j * 16 + (lane & 15);
        int c = ((ks << 2) + (lane >> 4)) ^ (r & 7);
        bfr[j] = *(const short8*)&bufB[r * 64 + c * 8];
      }
      #pragma unroll
      for (int i = 0; i < 8; i++)
        #pragma unroll
        for (int j = 0; j < NR; j++)
          acc[i][j] = __builtin_amdgcn_mfma_f32_16x16x32_bf16(af[i], bfr[j], acc[i][j], 0, 0, 0);
    }
    __syncthreads();                // drains vmcnt(0)+lgkmcnt(0) then barrier
    cur ^= 1;
  }
  #pragma unroll
  for (int i = 0; i < 8; i++) {
    #pragma unroll
    for (int j = 0; j < NR; j++) {
      int col = bn + wn + j * 16 + (lane & 15);
      float bv = (EPI == 1) ? bias[col] : 0.f;
      #pragma unroll
      for (int r = 0; r < 4; r++) {
        int row = bm + wm + i * 16 + (lane >> 4) * 4 + r;
        float v = acc[i][j][r];
        if (EPI == 1) v = softplus_f(v + bv);
        if (OUTBF) ((unsigned short*)Cp)[(size_t)row * N + col] = f2bf(v);
        else       ((float*)Cp)[(size_t)row * N + col] = v;
      }
    }
  }
}

// ---------------- causal depthwise conv (k=4) + bias + SiLU -> bf16 ----
__global__ __launch_bounds__(256) void conv_silu_k(
    const unsigned short* __restrict__ xz, const float* __restrict__ cw,
    const float* __restrict__ cb, unsigned short* __restrict__ xa)
{
  int v = blockIdx.x * 256 + threadIdx.x;   // over BL*DI/8
  int d8 = (v & (DI/8 - 1)) * 8;
  int bl = v >> 8;
  int l  = bl & (LL - 1);
  float acc[8];
  #pragma unroll
  for (int j = 0; j < 8; j++) acc[j] = cb[d8 + j];
  size_t rowb = (size_t)bl * (2 * DI) + d8;
  #pragma unroll
  for (int k = 0; k < 4; k++) {
    int ls = l - 3 + k;
    if (ls >= 0) {
      ushort8 xv = *(const ushort8*)&xz[rowb + (size_t)(k - 3) * (2 * DI)];
      #pragma unroll
      for (int j = 0; j < 8; j++) acc[j] += bf2f(xv[j]) * cw[(d8 + j) * 4 + k];
    }
  }
  ushort8 o;
  #pragma unroll
  for (int j = 0; j < 8; j++) o[j] = f2bf(silu_f(acc[j]));
  *(ushort8*)&xa[(size_t)bl * DI + d8] = o;
}

// ---------------- bc = xa @ x_proj_w^T  (N=32) -------------------------
__global__ __launch_bounds__(256) void bc_k(
    const unsigned short* __restrict__ xa, const unsigned short* __restrict__ w,
    float* __restrict__ bc)
{
  __shared__ unsigned short sx[8 * DI];
  const int t = threadIdx.x;
  const size_t base = (size_t)blockIdx.x * 8 * DI;
  #pragma unroll
  for (int it = 0; it < 8; it++) {
    int v = t + it * 256;
    *(ushort8*)&sx[v * 8] = *(const ushort8*)&xa[base + (size_t)v * 8];
  }
  __syncthreads();
  const int m = t >> 5, n = t & 31;
  const unsigned short* wr = w + (size_t)n * DI;
  const unsigned short* xr = sx + m * DI;
  float acc = 0.f;
  #pragma unroll 4
  for (int k = 0; k < DI; k += 8) {
    ushort8 xv = *(const ushort8*)&xr[k];
    ushort8 wv = *(const ushort8*)&wr[k];
    #pragma unroll
    for (int j = 0; j < 8; j++) acc += bf2f(xv[j]) * bf2f(wv[j]);
  }
  bc[(size_t)(blockIdx.x * 8 + m) * 32 + n] = acc;
}

// ---------------- chunked selective scan (dlt bf16, S bf16) ------------
__global__ __launch_bounds__(256) void scan_part1(
    const unsigned short* __restrict__ dlt, const unsigned short* __restrict__ xa,
    const float* __restrict__ bc, const float* __restrict__ A_log,
    unsigned short* __restrict__ S_bf, float* __restrict__ sumdlt)
{
  const int bid = blockIdx.x;           // NB*NC*8 = 1024
  const int b = bid >> 9;
  const int c = (bid >> 3) & (NC - 1);
  const int dg = bid & 7;
  const int t = threadIdx.x;
  const int d = dg * 256 + t;
  float Ac[16];
  #pragma unroll
  for (int n = 0; n < 16; n++) Ac[n] = -__expf(A_log[d * 16 + n]);
  __shared__ float sB[LC][16];
  for (int e = t; e < LC * 16; e += 256) {
    int l = e >> 4, n = e & 15;
    sB[l][n] = bc[(size_t)(b * LL + c * LC + l) * 32 + n];
  }
  __syncthreads();
  float h[16] = {};
  float sd = 0.f;
  size_t rowbase = (size_t)(b * LL + c * LC) * DI + d;
  for (int l = 0; l < LC; l++) {
    float dl = bf2f(dlt[rowbase + (size_t)l * DI]);
    float u  = bf2f(xa[rowbase + (size_t)l * DI]);
    float w = dl * u;
    sd += dl;
    #pragma unroll
    for (int n = 0; n < 16; n++) {
      float dA = __expf(dl * Ac[n]);
      h[n] = dA * h[n] + w * sB[l][n];
    }
  }
  unsigned short* Sp = S_bf + ((size_t)(b * NC + c) * DI + d) * 16;
  ushort8 s0, s1;
  #pragma unroll
  for (int n = 0; n < 8; n++) { s0[n] = f2bf(h[n]); s1[n] = f2bf(h[8 + n]); }
  *(ushort8*)&Sp[0] = s0;
  *(ushort8*)&Sp[8] = s1;
  sumdlt[(size_t)(b * NC + c) * DI + d] = sd;
}

__global__ __launch_bounds__(256) void scan_combine(
    const float* __restrict__ A_log, const float* __restrict__ sumdlt,
    unsigned short* __restrict__ S_bf)
{
  int tid = blockIdx.x * 256 + threadIdx.x;   // NB*DI*16 = 65536
  int n = tid & 15;
  int d = (tid >> 4) & (DI - 1);
  int b = tid >> 15;
  float Ac = -__expf(A_log[d * 16 + n]);
  float h = 0.f;
  for (int c = 0; c < NC; c++) {
    size_t idx = ((size_t)(b * NC + c) * DI + d) * 16 + n;
    float S = bf2f(S_bf[idx]);
    float P = __expf(sumdlt[(size_t)(b * NC + c) * DI + d] * Ac);
    S_bf[idx] = f2bf(h);
    h = P * h + S;
  }
}

__global__ __launch_bounds__(256) void scan_part2(
    const unsigned short* __restrict__ dlt, const unsigned short* __restrict__ xa,
    const float* __restrict__ bc, const float* __restrict__ A_log,
    const float* __restrict__ Dp, const unsigned short* __restrict__ xz,
    const unsigned short* __restrict__ Hin, unsigned short* __restrict__ y)
{
  const int bid = blockIdx.x;
  const int b = bid >> 9;
  const int c = (bid >> 3) & (NC - 1);
  const int dg = bid & 7;
  const int t = threadIdx.x;
  const int d = dg * 256 + t;
  float Ac[16];
  #pragma unroll
  for (int n = 0; n < 16; n++) Ac[n] = -__expf(A_log[d * 16 + n]);
  __shared__ float sB[LC][16];
  __shared__ float sC[LC][16];
  for (int e = t; e < LC * 16; e += 256) {
    int l = e >> 4, n = e & 15;
    size_t row = (size_t)(b * LL + c * LC + l) * 32;
    sB[l][n] = bc[row + n];
    sC[l][n] = bc[row + 16 + n];
  }
  __syncthreads();
  float h[16];
  const unsigned short* Hp = Hin + ((size_t)(b * NC + c) * DI + d) * 16;
  ushort8 h0 = *(const ushort8*)&Hp[0];
  ushort8 h1 = *(const ushort8*)&Hp[8];
  #pragma unroll
  for (int n = 0; n < 8; n++) { h[n] = bf2f(h0[n]); h[8 + n] = bf2f(h1[n]); }
  const float Dv = Dp[d];
  size_t rowbase = (size_t)(b * LL + c * LC) * DI + d;
  for (int l = 0; l < LC; l++) {
    float dl = bf2f(dlt[rowbase + (size_t)l * DI]);
    float u  = bf2f(xa[rowbase + (size_t)l * DI]);
    float w = dl * u;
    float ya = 0.f;
    #pragma unroll
    for (int n = 0; n < 16; n++) {
      float dA = __expf(dl * Ac[n]);
      h[n] = dA * h[n] + w * sB[l][n];
      ya += h[n] * sC[l][n];
    }
    float zz = bf2f(xz[(size_t)(b * LL + c * LC + l) * (2 * DI) + DI + d]);
    y[rowbase + (size_t)l * DI] = f2bf((ya + u * Dv) * silu_f(zz));
  }
}

extern "C" void kernel_launch(void* const* d_in, const int* in_sizes, int n_in,
                              void* d_out, int out_size, void* d_ws, size_t ws_size,
                              hipStream_t stream)
{
  const float* x    = (const float*)d_in[0];
  const float* Win  = (const float*)d_in[1];
  const float* cw   = (const float*)d_in[2];
  const float* cb   = (const float*)d_in[3];
  const float* Wxp  = (const float*)d_in[4];
  const float* Wdt  = (const float*)d_in[5];
  const float* bdt  = (const float*)d_in[6];
  const float* Alog = (const float*)d_in[7];
  const float* Dp   = (const float*)d_in[8];
  const float* Wout = (const float*)d_in[9];
  float* out = (float*)d_out;

  float* ws = (float*)d_ws;
  unsigned short* dlt_bf = (unsigned short*)ws;      //  8,388,608 us
  float* bcb    = ws + 4194304;                      //    131,072 f
  unsigned short* S_bf = (unsigned short*)(bcb + 131072);  // 4,194,304 us
  float* sumdlt = (float*)(S_bf + 4194304);          //    262,144 f
  unsigned short* xz_bf = (unsigned short*)(sumdlt + 262144); // 16,777,216 us
  unsigned short* xa_bf = xz_bf + 16777216;          //  8,388,608 us
  unsigned short* y_bf  = xa_bf + 8388608;           //  8,388,608 us
  unsigned short* x_bf  = y_bf;                      // 4,194,304 us (dead before y written)
  unsigned short* win_bf= y_bf + 4194304;            // 4,194,304 us (dead before y written)
  unsigned short* wbuf  = y_bf + 8388608;            //  4,194,304 us (Wdt, then Wout)
  unsigned short* wxp_bf= wbuf + 4194304;            //     65,536 us

  // 0) upfront conversions: x, Win, Wdt, Wxp (counts in 2048-elem blocks)
  f2b_multi<<<dim3(2048 + 2048 + 2048 + 32), dim3(256), 0, stream>>>(
      x, x_bf, 2048, Win, win_bf, 2048, Wdt, wbuf, 2048, Wxp, wxp_bf, 32);
  // 1) xz = x @ in_proj_w^T   [4096 x 4096], K=1024 -> bf16   grid 16x16=256
  gemm2<256,0,1><<<dim3(256), dim3(512), 0, stream>>>(x_bf, win_bf, nullptr, xz_bf, BL, 2*DI, DM);
  // 2) x_act = silu(causal_conv(x_ssm)) -> bf16
  conv_silu_k<<<dim3(BL*DI/8/256), dim3(256), 0, stream>>>(xz_bf, cw, cb, xa_bf);
  // 3) delta = softplus(x_act @ dt_proj_w^T + b)  [4096x2048] K=2048 -> bf16, grid 256
  gemm2<128,1,1><<<dim3(256), dim3(512), 0, stream>>>(xa_bf, wbuf, bdt, dlt_bf, BL, DI, DI);
  // convert Wout into wbuf (stream-ordered after dt GEMM consumed Wdt)
  f2b_k<<<dim3(DM*DI/2048), dim3(256), 0, stream>>>(Wout, wbuf, DM*DI);
  // 4) bc = x_act @ x_proj_w^T   [4096 x 32]
  bc_k<<<dim3(BL/8), dim3(256), 0, stream>>>(xa_bf, wxp_bf, bcb);
  // 5) chunked selective scan (S state in bf16)
  scan_part1<<<dim3(NB*NC*8), dim3(256), 0, stream>>>(dlt_bf, xa_bf, bcb, Alog, S_bf, sumdlt);
  scan_combine<<<dim3(NB*DI*DS/256), dim3(256), 0, stream>>>(Alog, sumdlt, S_bf);
  scan_part2<<<dim3(NB*NC*8), dim3(256), 0, stream>>>(dlt_bf, xa_bf, bcb, Alog, Dp, xz_bf, S_bf, y_bf);
  // 6) out = y @ out_proj_w^T   [4096 x 1024], K=2048 -> fp32  grid 16x16=256
  gemm2<64,0,0><<<dim3(256), dim3(512), 0, stream>>>(y_bf, wbuf, nullptr, out, BL, DM, DI);
}